// Round 2
// baseline (107.737 us; speedup 1.0000x reference)
//
#include <hip/hip_runtime.h>
#include <math.h>

#define VOCAB 100000
#define EMB 128
#define BATCH 16384
#define NPOS 4
#define NNEG 20
#define EPSV 1e-3f

#define NBLOCKS 2048
#define NTHREADS 256
#define WAVES_PER_BLOCK (NTHREADS / 64)                       // 4
#define ELEMS_PER_WAVE (BATCH / (NBLOCKS * WAVES_PER_BLOCK))  // 2
#define COUNTER_OFF_BYTES 32768                               // past 4096 partial floats

// Fused kernel: gather + dot + sigmoid/log partials, then last-finished block
// performs the deterministic final reduction (fixed combination order).
__global__ __launch_bounds__(NTHREADS) void w2v_fused(
    const int* __restrict__ x,
    const int* __restrict__ pos,
    const int* __restrict__ neg,
    const float* __restrict__ emb,
    const float* __restrict__ outw,
    float* __restrict__ partials,
    unsigned int* __restrict__ counter,
    float* __restrict__ out)
{
    const int tid  = threadIdx.x;
    const int lane = tid & 63;
    const int wid  = tid >> 6;
    const int g    = lane >> 4;   // group 0..3 (16 lanes each)
    const int i    = lane & 15;   // lane within group
    const int wv   = blockIdx.x * WAVES_PER_BLOCK + wid;

    float pos_acc = 0.0f;
    float neg_acc = 0.0f;

#pragma unroll
    for (int e = 0; e < ELEMS_PER_WAVE; ++e) {
        const int b  = wv * ELEMS_PER_WAVE + e;
        const int xb = x[b];

        // Preload all 24 sample indices across lanes 0..23 (one predicated load),
        // broadcast later via __shfl — removes 6 dependent loads from the chain.
        int myidx = 0;
        if (lane < NPOS)            myidx = pos[b * NPOS + lane];
        else if (lane < NPOS + NNEG) myidx = neg[b * NNEG + (lane - NPOS)];

        // emb row: lane i reads contiguous halves [i] and [i+16] (each wave-load
        // covers a contiguous 256B half-row -> 4 line-accesses/row, not 8).
        const float4* embr = (const float4*)(emb + (long)xb * EMB);
        const float4 e0 = embr[i];
        const float4 e1 = embr[i + 16];

        float z0, z1, z2, z3, z4, z5;
#pragma unroll
        for (int iter = 0; iter < 6; ++iter) {
            const int src  = (iter == 0) ? g : (NPOS + (iter - 1) * 4 + g);
            const int sidx = __shfl(myidx, src);

            const float4* wr = (const float4*)(outw + (long)sidx * EMB);
            const float4 w0 = wr[i];
            const float4 w1 = wr[i + 16];

            float p = e0.x * w0.x + e0.y * w0.y + e0.z * w0.z + e0.w * w0.w
                    + e1.x * w1.x + e1.y * w1.y + e1.z * w1.z + e1.w * w1.w;

            // 16-lane butterfly reduce (masks < 16 stay within the group)
            p += __shfl_xor(p, 1);
            p += __shfl_xor(p, 2);
            p += __shfl_xor(p, 4);
            p += __shfl_xor(p, 8);

            if      (iter == 0) z0 = p;
            else if (iter == 1) z1 = p;
            else if (iter == 2) z2 = p;
            else if (iter == 3) z3 = p;
            else if (iter == 4) z4 = p;
            else                z5 = p;
        }

        // One transcendental pass per elem: lane i<6 of group g finalizes
        // sample (iter=i, group=g).
        if (i < 6) {
            float z = z0;
            z = (i == 1) ? z1 : z;
            z = (i == 2) ? z2 : z;
            z = (i == 3) ? z3 : z;
            z = (i == 4) ? z4 : z;
            z = (i == 5) ? z5 : z;
            const float t = __expf(-z);
            const float s = 1.0f / (1.0f + t);          // sigmoid(z)
            const float v = (i == 0) ? s : (1.0f - s + EPSV);
            const float term = __logf(v);
            if (i == 0) pos_acc += term;
            else        neg_acc += term;
        }
    }

    // wave-wide butterfly reduce
#pragma unroll
    for (int m = 1; m < 64; m <<= 1) {
        pos_acc += __shfl_xor(pos_acc, m);
        neg_acc += __shfl_xor(neg_acc, m);
    }

    __shared__ float sp[WAVES_PER_BLOCK];
    __shared__ float sn[WAVES_PER_BLOCK];
    __shared__ int   sLast;
    if (lane == 0) { sp[wid] = pos_acc; sn[wid] = neg_acc; }
    __syncthreads();
    if (tid == 0) {
        float tp = 0.0f, tn = 0.0f;
#pragma unroll
        for (int w = 0; w < WAVES_PER_BLOCK; ++w) { tp += sp[w]; tn += sn[w]; }
        partials[2 * blockIdx.x]     = tp;
        partials[2 * blockIdx.x + 1] = tn;
        __threadfence();                       // release partials before counting
        const unsigned prev = atomicAdd(counter, 1u);
        sLast = (prev == NBLOCKS - 1) ? 1 : 0;
    }
    __syncthreads();

    if (sLast) {
        __threadfence();                       // acquire all partials
        // Fixed-order tree reduction -> deterministic result every launch.
        volatile const float* vp = partials;   // bypass register/L1 caching
        float tp = 0.0f, tn = 0.0f;
        for (int k = tid; k < NBLOCKS; k += NTHREADS) {
            tp += vp[2 * k];
            tn += vp[2 * k + 1];
        }
#pragma unroll
        for (int m = 1; m < 64; m <<= 1) {
            tp += __shfl_xor(tp, m);
            tn += __shfl_xor(tn, m);
        }
        if (lane == 0) { sp[wid] = tp; sn[wid] = tn; }
        __syncthreads();
        if (tid == 0) {
            const float fp = sp[0] + sp[1] + sp[2] + sp[3];
            const float fn = sn[0] + sn[1] + sn[2] + sn[3];
            out[0] = -fp / (float)(BATCH * NPOS) - fn / (float)(BATCH * NNEG);
        }
    }
}

extern "C" void kernel_launch(void* const* d_in, const int* in_sizes, int n_in,
                              void* d_out, int out_size, void* d_ws, size_t ws_size,
                              hipStream_t stream) {
    const int*   x    = (const int*)d_in[0];
    const int*   pos  = (const int*)d_in[1];
    const int*   neg  = (const int*)d_in[2];
    const float* emb  = (const float*)d_in[3];
    const float* outw = (const float*)d_in[4];
    float* out = (float*)d_out;

    float*        partials = (float*)d_ws;                                  // 4096 floats
    unsigned int* counter  = (unsigned int*)((char*)d_ws + COUNTER_OFF_BYTES);

    // Counter must start at 0 every launch (ws is poisoned to 0xAA once).
    hipMemsetAsync(counter, 0, sizeof(unsigned int), stream);
    w2v_fused<<<NBLOCKS, NTHREADS, 0, stream>>>(x, pos, neg, emb, outw,
                                                partials, counter, out);
}

// Round 3
// 38.588 us; speedup vs baseline: 2.7919x; 2.7919x over previous
//
#include <hip/hip_runtime.h>
#include <math.h>

#define VOCAB 100000
#define EMB 128
#define BATCH 16384
#define NPOS 4
#define NNEG 20
#define NSAMP (NPOS + NNEG)   // 24
#define EPSV 1e-3f

#define NBLOCKS 4096
#define NTHREADS 256
#define WAVES_PER_BLOCK (NTHREADS / 64)   // 4; one batch element per wave

// One wave per batch element. Each half-wave (32 lanes x float4 = 512B) reads
// one full row per load instruction; the 12 W-loads are mutually independent
// so the wave keeps ~12 vmem ops in flight (MLP), then reduces.
__global__ __launch_bounds__(NTHREADS) void w2v_main(
    const int* __restrict__ x,
    const int* __restrict__ pos,
    const int* __restrict__ neg,
    const float* __restrict__ emb,
    const float* __restrict__ outw,
    float* __restrict__ partials)
{
    const int tid  = threadIdx.x;
    const int lane = tid & 63;
    const int wid  = tid >> 6;
    const int half = lane >> 5;   // 0 or 1
    const int li   = lane & 31;   // lane within half-wave

    const int b  = blockIdx.x * WAVES_PER_BLOCK + wid;  // batch element
    const int xb = x[b];

    // lanes 0..23 each hold one sample index (0..3 pos, 4..23 neg)
    int myidx = 0;
    if (lane < NPOS)             myidx = pos[b * NPOS + lane];
    else if (lane < NSAMP)       myidx = neg[b * NNEG + (lane - NPOS)];

    // emb row: lane li holds floats [4*li, 4*li+4); both halves duplicate.
    const float4 e = ((const float4*)(emb + (long)xb * EMB))[li];

    // 12 independent row loads; half h, load j covers sample s = 2*j + h.
    float z[12];
#pragma unroll
    for (int j = 0; j < 12; ++j) {
        const int s = __shfl(myidx, 2 * j + half);
        const float4 w = ((const float4*)(outw + (long)s * EMB))[li];
        z[j] = e.x * w.x + e.y * w.y + e.z * w.z + e.w * w.w;
    }

    // 32-lane butterfly reduce per sample (masks < 32 stay within the half)
#pragma unroll
    for (int j = 0; j < 12; ++j) {
        z[j] += __shfl_xor(z[j], 1);
        z[j] += __shfl_xor(z[j], 2);
        z[j] += __shfl_xor(z[j], 4);
        z[j] += __shfl_xor(z[j], 8);
        z[j] += __shfl_xor(z[j], 16);
    }

    // One transcendental pass: lane (h*32 + j), j<12, finalizes sample 2j+h.
    float pos_acc = 0.0f, neg_acc = 0.0f;
    if (li < 12) {
        float zz = z[0];
#pragma unroll
        for (int j = 1; j < 12; ++j) zz = (li == j) ? z[j] : zz;  // compile-time idx
        const int s = 2 * li + half;
        const float t  = __expf(-zz);
        const float sg = 1.0f / (1.0f + t);               // sigmoid(z)
        const float v  = (s < NPOS) ? sg : (1.0f - sg + EPSV);
        const float term = __logf(v);
        if (s < NPOS) pos_acc = term;
        else          neg_acc = term;
    }

    // wave-wide butterfly reduce (sums both halves)
#pragma unroll
    for (int m = 1; m < 64; m <<= 1) {
        pos_acc += __shfl_xor(pos_acc, m);
        neg_acc += __shfl_xor(neg_acc, m);
    }

    __shared__ float sp[WAVES_PER_BLOCK];
    __shared__ float sn[WAVES_PER_BLOCK];
    if (lane == 0) { sp[wid] = pos_acc; sn[wid] = neg_acc; }
    __syncthreads();
    if (tid == 0) {
        float tp = 0.0f, tn = 0.0f;
#pragma unroll
        for (int w = 0; w < WAVES_PER_BLOCK; ++w) { tp += sp[w]; tn += sn[w]; }
        partials[2 * blockIdx.x]     = tp;
        partials[2 * blockIdx.x + 1] = tn;
    }
}

// Finalize: single block reduces 4096 block partials, writes the scalar loss.
__global__ __launch_bounds__(1024) void w2v_final(
    const float* __restrict__ partials, float* __restrict__ out)
{
    const int tid  = threadIdx.x;
    const int lane = tid & 63;
    const int wid  = tid >> 6;

    float tp = 0.0f, tn = 0.0f;
    for (int k = tid; k < NBLOCKS; k += 1024) {
        tp += partials[2 * k];
        tn += partials[2 * k + 1];
    }
#pragma unroll
    for (int m = 1; m < 64; m <<= 1) {
        tp += __shfl_xor(tp, m);
        tn += __shfl_xor(tn, m);
    }
    __shared__ float sp[16];
    __shared__ float sn[16];
    if (lane == 0) { sp[wid] = tp; sn[wid] = tn; }
    __syncthreads();
    if (tid == 0) {
        float fp = 0.0f, fn = 0.0f;
#pragma unroll
        for (int w = 0; w < 16; ++w) { fp += sp[w]; fn += sn[w]; }
        out[0] = -fp / (float)(BATCH * NPOS) - fn / (float)(BATCH * NNEG);
    }
}

extern "C" void kernel_launch(void* const* d_in, const int* in_sizes, int n_in,
                              void* d_out, int out_size, void* d_ws, size_t ws_size,
                              hipStream_t stream) {
    const int*   x    = (const int*)d_in[0];
    const int*   pos  = (const int*)d_in[1];
    const int*   neg  = (const int*)d_in[2];
    const float* emb  = (const float*)d_in[3];
    const float* outw = (const float*)d_in[4];
    float* out = (float*)d_out;
    float* partials = (float*)d_ws;   // 8192 floats, fully rewritten each launch

    w2v_main<<<NBLOCKS, NTHREADS, 0, stream>>>(x, pos, neg, emb, outw, partials);
    w2v_final<<<1, 1024, 0, stream>>>(partials, out);
}